// Round 5
// baseline (219.172 us; speedup 1.0000x reference)
//
#include <hip/hip_runtime.h>
#include <hip/hip_bf16.h>
#include <cstdint>
#include <math.h>

#define S_LEN 2048
#define DM 1024
#define NQKV 1536
#define MROWS 4096   // B * S

typedef __attribute__((ext_vector_type(8))) short short8;
typedef __attribute__((ext_vector_type(4))) short short4v;
typedef __attribute__((ext_vector_type(4))) float f32x4;

// compiler-level memory ordering point (same-wave LDS RAW; HW is in-order)
#define MEMBAR() __asm__ __volatile__("" ::: "memory")

// 0.125 (1/sqrt(64)) * log2(e), folded into Q at RoPE time
#define QFOLD 0.18033688011112042f

__device__ __forceinline__ short f2bf(float x) {
  union { float f; uint32_t u; } v; v.f = x;
  uint32_t r = (v.u + 0x7fffu + ((v.u >> 16) & 1u)) >> 16;
  return (short)(uint16_t)r;
}

__device__ __forceinline__ uint32_t pk2(float a, float b) {
  __hip_bfloat162 h = __float22bfloat162_rn(make_float2(a, b));
  union { __hip_bfloat162 h2; uint32_t u; } cv; cv.h2 = h;
  return cv.u;
}

// ---------------- fp32 -> bf16 vectorized convert ----------------
__global__ void f32_to_bf16_vec(const float* __restrict__ in, short* __restrict__ out, int n4) {
  int i = blockIdx.x * blockDim.x + threadIdx.x;
  if (i < n4) {
    float4 v = ((const float4*)in)[i];
    short4 o;
    o.x = f2bf(v.x); o.y = f2bf(v.y); o.z = f2bf(v.z); o.w = f2bf(v.w);
    ((short4*)out)[i] = o;
  }
}

// ---------------- fp32 [R][C] -> bf16 transposed dst[c*R + r] ----------------
__global__ __launch_bounds__(256) void transpose_f32_bf16(const float* __restrict__ src,
    short* __restrict__ dst, int R, int C) {
  __shared__ short T[64 * 72];
  const int r0 = blockIdx.x * 64, c0 = blockIdx.y * 64;
  const int tid = threadIdx.x;
  #pragma unroll
  for (int i = 0; i < 4; ++i) {
    int chunk = tid + i * 256;
    int r = chunk >> 4, cc = (chunk & 15) * 4;
    float4 v = *(const float4*)&src[(size_t)(r0 + r) * C + c0 + cc];
    T[(cc + 0) * 72 + r] = f2bf(v.x);
    T[(cc + 1) * 72 + r] = f2bf(v.y);
    T[(cc + 2) * 72 + r] = f2bf(v.z);
    T[(cc + 3) * 72 + r] = f2bf(v.w);
  }
  __syncthreads();
  #pragma unroll
  for (int i = 0; i < 2; ++i) {
    int chunk = tid + i * 256;
    int rr = chunk >> 3, kk = (chunk & 7) * 8;
    *(uint4*)&dst[(size_t)(c0 + rr) * R + r0 + kk] = *(uint4*)&T[rr * 72 + kk];
  }
}

// ---------------- bf16 MFMA GEMM, m97-style global_load_lds staging ----------------
// C[M][N] = A[M][K] * BT[N][K]^T. 128x128 tile, BK=64, unpadded LDS (lane-contiguous
// dest required by global_load_lds: wave-uniform base + lane*16B).
#define BM 128
#define BN 128
#define BKT 64

__global__ __launch_bounds__(256) void gemm_bf16(const short* __restrict__ A,
    const short* __restrict__ BT, float* __restrict__ C, int M, int N, int K) {
  __shared__ short As[BM * BKT];   // 16 KB, row-major [128][64]
  __shared__ short Bs[BN * BKT];   // 16 KB
  const int tid = threadIdx.x;
  const int wave = tid >> 6, lane = tid & 63;
  const int quad = lane >> 4, l15 = lane & 15;
  const int wm = (wave >> 1) * 64, wn = (wave & 1) * 64;
  const int m0 = blockIdx.y * BM, n0 = blockIdx.x * BN;

  // staging map: issue j by wave w covers tile rows w*32+j*8 .. +7 (8 rows x 64 cols
  // = 1024B = 64 lanes x 16B); lane's global addr must equal ldsbase + lane*16.
  const int sr = wave * 32 + (lane >> 3);     // + j*8
  const int scol = (lane & 7) * 8;

  f32x4 acc[4][4] = {};

  for (int k0 = 0; k0 < K; k0 += BKT) {
    __syncthreads();
    #pragma unroll
    for (int j = 0; j < 4; ++j) {
      const int r = sr + j * 8;
      __builtin_amdgcn_global_load_lds(
          (const __attribute__((address_space(1))) void*)&A[(size_t)(m0 + r) * K + k0 + scol],
          (__attribute__((address_space(3))) void*)&As[(wave * 4 + j) * 512],
          16, 0, 0);
      __builtin_amdgcn_global_load_lds(
          (const __attribute__((address_space(1))) void*)&BT[(size_t)(n0 + r) * K + k0 + scol],
          (__attribute__((address_space(3))) void*)&Bs[(wave * 4 + j) * 512],
          16, 0, 0);
    }
    __syncthreads();   // drains vmcnt(0) -> staged data visible
    #pragma unroll
    for (int ks = 0; ks < 2; ++ks) {
      short8 af[4], bfr[4];
      #pragma unroll
      for (int mi = 0; mi < 4; ++mi)
        af[mi] = *(const short8*)&As[(wm + mi*16 + l15)*BKT + ks*32 + quad*8];
      #pragma unroll
      for (int ni = 0; ni < 4; ++ni)
        bfr[ni] = *(const short8*)&Bs[(wn + ni*16 + l15)*BKT + ks*32 + quad*8];
      #pragma unroll
      for (int mi = 0; mi < 4; ++mi)
        #pragma unroll
        for (int ni = 0; ni < 4; ++ni)
          acc[mi][ni] = __builtin_amdgcn_mfma_f32_16x16x32_bf16(af[mi], bfr[ni], acc[mi][ni], 0, 0, 0);
    }
  }
  #pragma unroll
  for (int mi = 0; mi < 4; ++mi)
    #pragma unroll
    for (int ni = 0; ni < 4; ++ni)
      #pragma unroll
      for (int r = 0; r < 4; ++r)
        C[(size_t)(m0 + wm + mi*16 + quad*4 + r)*N + (n0 + wn + ni*16 + l15)] = acc[mi][ni][r];
}

// ---------------- RoPE + bf16 pack; Q gets scale*log2e folded in ----------------
__global__ void rope_kernel(const float* __restrict__ qkv, short* __restrict__ Qb,
                            short* __restrict__ Kb, short* __restrict__ Vb) {
  __shared__ float csn[64];
  const int row = blockIdx.x;
  const int s = row & (S_LEN - 1);
  const int tid = threadIdx.x;
  const float* rp = qkv + (size_t)row * NQKV;
  if (tid < 32) {
    float inv = exp2f(-(float)tid * 0.41524101186092029f);  // log2(10000)/32
    float ang = (float)s * inv;
    csn[tid] = cosf(ang);
    csn[tid + 32] = sinf(ang);
  }
  __syncthreads();
  #pragma unroll
  for (int i = 0; i < 2; ++i) {
    int p = tid + i * 256;
    int hh = p >> 5, j = p & 31;
    float cs = csn[j], sn = csn[j + 32];
    float x1 = rp[hh*64 + j], x2 = rp[hh*64 + j + 32];
    Qb[(size_t)row*1024 + hh*64 + j]      = f2bf((x1*cs - x2*sn) * QFOLD);
    Qb[(size_t)row*1024 + hh*64 + j + 32] = f2bf((x2*cs + x1*sn) * QFOLD);
  }
  if (tid < 128) {
    int hh = tid >> 5, j = tid & 31;
    float cs = csn[j], sn = csn[j + 32];
    float x1 = rp[1024 + hh*64 + j], x2 = rp[1024 + hh*64 + j + 32];
    Kb[(size_t)row*256 + hh*64 + j]      = f2bf(x1*cs - x2*sn);
    Kb[(size_t)row*256 + hh*64 + j + 32] = f2bf(x2*cs + x1*sn);
  }
  Vb[(size_t)row*256 + tid] = f2bf(rp[1280 + tid]);
}

// ---------------- V transpose: Vb[b*S+s][kvh*64+d] -> Vt[(b*4+kvh)*64+d][s] ----------------
__global__ __launch_bounds__(256) void transpose_v(const short* __restrict__ Vb,
                                                   short* __restrict__ Vt) {
  __shared__ short T[64 * 72];
  const int s0 = blockIdx.x * 64;
  const int bh = blockIdx.y;
  const int b = bh >> 2, kvh = bh & 3;
  const int tid = threadIdx.x;
  #pragma unroll
  for (int i = 0; i < 2; ++i) {
    int chunk = tid + i * 256;
    int r = chunk >> 3, c = (chunk & 7) * 8;
    short8 v = *(const short8*)&Vb[(size_t)(b*S_LEN + s0 + r)*256 + kvh*64 + c];
    #pragma unroll
    for (int t = 0; t < 8; ++t) T[(c + t) * 72 + r] = v[t];
  }
  __syncthreads();
  #pragma unroll
  for (int i = 0; i < 2; ++i) {
    int chunk = tid + i * 256;
    int rr = chunk >> 3, kk = (chunk & 7) * 8;
    *(uint4*)&Vt[(size_t)(bh*64 + rr)*S_LEN + s0 + kk] = *(uint4*)&T[rr * 72 + kk];
  }
}

// ---------------- causal GQA flash attention v4 ----------------
// grid 256 = (b,kvh,hh,j). Each block: tiles j then 31-j => exactly 17 KV events
// (perfect balance). 4 waves = 2 heads x 2 row-halves. Transposed-S softmax.
#define PSTR 136

__global__ __launch_bounds__(256, 1) void fattn4(const short* __restrict__ Qb,
    const short* __restrict__ Kb, const short* __restrict__ Vt, short* __restrict__ Ctx) {
  __shared__ short Ks[128 * 72];        // K tile [kv 128][d 64]
  __shared__ short Vts[64 * PSTR];      // V^T tile [d 64][kv 128]
  __shared__ short Ps[4 * 32 * PSTR];   // per-wave P [q 32][kv 128]
  __shared__ float Asc[4 * 32];         // per-wave alpha / 1/l broadcast patch
  const int idx = blockIdx.x;
  const int j   = idx & 15;
  const int hh  = (idx >> 4) & 1;
  const int kvh = (idx >> 5) & 3;
  const int b   = idx >> 7;
  const int tid = threadIdx.x, wave = tid >> 6, lane = tid & 63;
  const int quad = lane >> 4, l15 = lane & 15;
  const int h    = kvh*4 + hh*2 + (wave >> 1);
  const int roff = (wave & 1) * 32;
  const size_t qbase  = (size_t)b * S_LEN * 1024;
  const size_t kbase  = (size_t)b * S_LEN * 256;
  const size_t vtbase = (size_t)(b*4 + kvh) * 64 * S_LEN;
  short* Psw = Ps + wave * 32 * PSTR;
  float* AscW = Asc + wave * 32;

  for (int half = 0; half < 2; ++half) {
    const int jt = half ? (31 - j) : j;
    const int q0 = jt * 64;
    const int ntiles = (jt >> 1) + 1;

    // Q B-frags (St = K * Q^T): B[k=d][n=q] == Q[q=l15][d=quad*8+..]
    short8 qf[2][2];
    #pragma unroll
    for (int mi = 0; mi < 2; ++mi)
      #pragma unroll
      for (int ks = 0; ks < 2; ++ks)
        qf[mi][ks] = *(const short8*)&Qb[qbase + (size_t)(q0 + roff + mi*16 + l15)*1024
                                         + h*64 + ks*32 + quad*8];

    f32x4 O[2][4] = {};
    float mm[2] = {-INFINITY, -INFINITY};
    float ll[2] = {0.f, 0.f};

    short8 kreg[4], vreg[4];
    #pragma unroll
    for (int i = 0; i < 4; ++i) {
      int chunk = tid + i * 256;
      int kr = chunk >> 3, kc = (chunk & 7) * 8;
      kreg[i] = *(const short8*)&Kb[kbase + (size_t)kr*256 + kvh*64 + kc];
      int vr = chunk >> 4, vc = (chunk & 15) * 8;
      vreg[i] = *(const short8*)&Vt[vtbase + (size_t)vr*S_LEN + vc];
    }

    for (int t = 0; t < ntiles; ++t) {
      const int k0 = t * 128;
      __syncthreads();
      #pragma unroll
      for (int i = 0; i < 4; ++i) {
        int chunk = tid + i * 256;
        int kr = chunk >> 3, kc = (chunk & 7) * 8;
        *(short8*)&Ks[kr*72 + kc] = kreg[i];
        int vr = chunk >> 4, vc = (chunk & 15) * 8;
        *(short8*)&Vts[vr*PSTR + vc] = vreg[i];
      }
      __syncthreads();
      if (t + 1 < ntiles) {
        const int kn = (t + 1) * 128;
        #pragma unroll
        for (int i = 0; i < 4; ++i) {
          int chunk = tid + i * 256;
          int kr = chunk >> 3, kc = (chunk & 7) * 8;
          kreg[i] = *(const short8*)&Kb[kbase + (size_t)(kn + kr)*256 + kvh*64 + kc];
          int vr = chunk >> 4, vc = (chunk & 15) * 8;
          vreg[i] = *(const short8*)&Vt[vtbase + (size_t)vr*S_LEN + kn + vc];
        }
      }

      // St = K Q^T : element (kv = k0+nt*16+quad*4+reg, q = q0+roff+mi*16+l15)
      f32x4 sc[2][8];
      #pragma unroll
      for (int nt = 0; nt < 8; ++nt) {
        short8 k0f = *(const short8*)&Ks[(nt*16 + l15)*72 + quad*8];
        short8 k1f = *(const short8*)&Ks[(nt*16 + l15)*72 + 32 + quad*8];
        #pragma unroll
        for (int mi = 0; mi < 2; ++mi) {
          f32x4 acc = {0.f, 0.f, 0.f, 0.f};
          acc = __builtin_amdgcn_mfma_f32_16x16x32_bf16(k0f, qf[mi][0], acc, 0, 0, 0);
          acc = __builtin_amdgcn_mfma_f32_16x16x32_bf16(k1f, qf[mi][1], acc, 0, 0, 0);
          sc[mi][nt] = acc;
        }
      }

      const bool lastt = (t == ntiles - 1);
      float al[2];
      #pragma unroll
      for (int mi = 0; mi < 2; ++mi) {
        const int qrow = q0 + roff + mi*16 + l15;
        if (lastt) {
          #pragma unroll
          for (int nt = 0; nt < 8; ++nt)
            #pragma unroll
            for (int r = 0; r < 4; ++r)
              if (k0 + nt*16 + quad*4 + r > qrow) sc[mi][nt][r] = -1e30f;
        }
        float mx = -1e30f;
        #pragma unroll
        for (int nt = 0; nt < 8; ++nt) {
          float a = fmaxf(sc[mi][nt][0], sc[mi][nt][1]);
          float c = fmaxf(sc[mi][nt][2], sc[mi][nt][3]);
          mx = fmaxf(mx, fmaxf(a, c));
        }
        mx = fmaxf(mx, __shfl_xor(mx, 16, 64));
        mx = fmaxf(mx, __shfl_xor(mx, 32, 64));
        float mn = fmaxf(mm[mi], mx);
        float alpha = exp2f(mm[mi] - mn);
        float sum = 0.f;
        #pragma unroll
        for (int nt = 0; nt < 8; ++nt) {
          float p0 = exp2f(sc[mi][nt][0] - mn);
          float p1 = exp2f(sc[mi][nt][1] - mn);
          float p2 = exp2f(sc[mi][nt][2] - mn);
          float p3 = exp2f(sc[mi][nt][3] - mn);
          sum += (p0 + p1) + (p2 + p3);
          union { uint2 u; short4v s; } pkc;
          pkc.u.x = pk2(p0, p1); pkc.u.y = pk2(p2, p3);
          *(short4v*)&Psw[(mi*16 + l15)*PSTR + nt*16 + quad*4] = pkc.s;
        }
        sum += __shfl_xor(sum, 16, 64);
        sum += __shfl_xor(sum, 32, 64);
        ll[mi] = ll[mi]*alpha + sum;
        mm[mi] = mn;
        al[mi] = alpha;
      }
      // broadcast alpha from q=l15 layout to C-layout rows q=quad*4+reg
      if (quad < 2) AscW[quad*16 + l15] = al[quad];
      MEMBAR();   // order LDS writes (P, alpha) before the reads below
      float av0[4], av1[4];
      #pragma unroll
      for (int r = 0; r < 4; ++r) {
        av0[r] = AscW[quad*4 + r];
        av1[r] = AscW[16 + quad*4 + r];
      }
      #pragma unroll
      for (int d = 0; d < 4; ++d)
        #pragma unroll
        for (int r = 0; r < 4; ++r) {
          O[0][d][r] *= av0[r];
          O[1][d][r] *= av1[r];
        }

      // O += P V
      #pragma unroll
      for (int ks = 0; ks < 4; ++ks) {
        short8 a0 = *(const short8*)&Psw[(0*16 + l15)*PSTR + ks*32 + quad*8];
        short8 a1 = *(const short8*)&Psw[(1*16 + l15)*PSTR + ks*32 + quad*8];
        #pragma unroll
        for (int d = 0; d < 4; ++d) {
          short8 bv = *(const short8*)&Vts[(d*16 + l15)*PSTR + ks*32 + quad*8];
          O[0][d] = __builtin_amdgcn_mfma_f32_16x16x32_bf16(a0, bv, O[0][d], 0, 0, 0);
          O[1][d] = __builtin_amdgcn_mfma_f32_16x16x32_bf16(a1, bv, O[1][d], 0, 0, 0);
        }
      }
    }

    // epilogue: broadcast 1/l, write ctx bf16
    if (quad < 2) AscW[quad*16 + l15] = 1.0f / ll[quad];
    MEMBAR();
    float lv0[4], lv1[4];
    #pragma unroll
    for (int r = 0; r < 4; ++r) {
      lv0[r] = AscW[quad*4 + r];
      lv1[r] = AscW[16 + quad*4 + r];
    }
    #pragma unroll
    for (int d = 0; d < 4; ++d)
      #pragma unroll
      for (int r = 0; r < 4; ++r) {
        int qrow0 = q0 + roff + quad*4 + r;
        Ctx[qbase + (size_t)qrow0*1024 + h*64 + d*16 + l15] = f2bf(O[0][d][r] * lv0[r]);
        int qrow1 = q0 + roff + 16 + quad*4 + r;
        Ctx[qbase + (size_t)qrow1*1024 + h*64 + d*16 + l15] = f2bf(O[1][d][r] * lv1[r]);
      }
  }
}

extern "C" void kernel_launch(void* const* d_in, const int* in_sizes, int n_in,
                              void* d_out, int out_size, void* d_ws, size_t ws_size,
                              hipStream_t stream) {
  const float* x  = (const float*)d_in[0];
  const float* Wq = (const float*)d_in[1];
  const float* Wk = (const float*)d_in[2];
  const float* Wv = (const float*)d_in[3];
  const float* Wo = (const float*)d_in[4];
  float* out = (float*)d_out;

  char* w = (char*)d_ws;
  short* Xb    = (short*)w;  w += (size_t)MROWS * DM * 2;
  short* WcatT = (short*)w;  w += (size_t)NQKV * DM * 2;
  short* WoT   = (short*)w;  w += (size_t)DM * DM * 2;
  float* QKVf  = (float*)w;  w += (size_t)MROWS * NQKV * 4;
  short* Qbuf  = (short*)w;  w += (size_t)MROWS * DM * 2;
  short* Kbuf  = (short*)w;  w += (size_t)MROWS * 256 * 2;
  short* Vbuf  = (short*)w;  w += (size_t)MROWS * 256 * 2;
  short* Vt    = (short*)w;  w += (size_t)8 * 64 * S_LEN * 2;
  short* Ctx   = (short*)QKVf;   // QKVf dead after rope

  f32_to_bf16_vec<<<dim3(4096), dim3(256), 0, stream>>>(x, Xb, MROWS * DM / 4);
  transpose_f32_bf16<<<dim3(16, 16), dim3(256), 0, stream>>>(Wq, WcatT, 1024, 1024);
  transpose_f32_bf16<<<dim3(16, 4),  dim3(256), 0, stream>>>(Wk, WcatT + (size_t)1024*1024, 1024, 256);
  transpose_f32_bf16<<<dim3(16, 4),  dim3(256), 0, stream>>>(Wv, WcatT + (size_t)1280*1024, 1024, 256);
  transpose_f32_bf16<<<dim3(16, 16), dim3(256), 0, stream>>>(Wo, WoT, 1024, 1024);

  gemm_bf16<<<dim3(NQKV / BN, MROWS / BM), dim3(256), 0, stream>>>(Xb, WcatT, QKVf, MROWS, NQKV, DM);
  rope_kernel<<<dim3(MROWS), dim3(256), 0, stream>>>(QKVf, Qbuf, Kbuf, Vbuf);
  transpose_v<<<dim3(32, 8), dim3(256), 0, stream>>>(Vbuf, Vt);
  fattn4<<<dim3(256), dim3(256), 0, stream>>>(Qbuf, Kbuf, Vt, Ctx);
  gemm_bf16<<<dim3(DM / BN, MROWS / BM), dim3(256), 0, stream>>>(Ctx, WoT, out, MROWS, DM, DM);
}